// Round 1
// 327.487 us; speedup vs baseline: 1.1465x; 1.1465x over previous
//
#include <hip/hip_runtime.h>
#include <math.h>

#define IH 2048
#define IW 2048
#define NBATCH 8
#define TILE 64
#define HALO 3
#define SIW 70           // logical halo tile (TILE + 2*HALO)
#define SI 71            // padded LDS row stride (odd -> conflict-free column reads)
#define ACT_TH 0.1f
#define IMP_TH 0.1f

// 1D Gaussian taps, sigma = 7/6, normalized (matches reference 2D outer product).
#define G0 0.0125602013f
#define G1 0.0788279697f
#define G2 0.2372960895f
#define G3 0.3426314790f

__device__ __forceinline__ float fsqrt_f(float x) { return __builtin_amdgcn_sqrtf(x); }
__device__ __forceinline__ float frcp_f(float x)  { return __builtin_amdgcn_rcpf(x); }

// ---------------- Kernel 1: per-batch max --------------------------------
__global__ __launch_bounds__(256) void batch_max_kernel(
    const float* __restrict__ x, unsigned int* __restrict__ maxbits)
{
    const int b = blockIdx.y;
    const float4* p = (const float4*)(x + (size_t)b * (size_t)(IH * IW));
    const int n4 = IH * IW / 4;
    float m = 0.0f;
    for (int i = blockIdx.x * blockDim.x + threadIdx.x; i < n4;
         i += gridDim.x * blockDim.x) {
        float4 v = p[i];
        m = fmaxf(m, fmaxf(fmaxf(v.x, v.y), fmaxf(v.z, v.w)));
    }
#pragma unroll
    for (int s = 1; s < 64; s <<= 1) m = fmaxf(m, __shfl_xor(m, s));
    __shared__ float sm[4];
    const int lane = threadIdx.x & 63, wv = threadIdx.x >> 6;
    if (lane == 0) sm[wv] = m;
    __syncthreads();
    if (threadIdx.x == 0) {
        m = fmaxf(fmaxf(sm[0], sm[1]), fmaxf(sm[2], sm[3]));
        // x is uniform[0,1): non-negative, so uint-bit compare == float compare
        atomicMax(&maxbits[b], __float_as_uint(m));
    }
}

// ---------------- Kernel 2: fused normalize + block stats ----------------
// Register-streaming separable conv: each thread owns one column (c) and a
// 16-row output group (g). Horizontal 7-tap results live in a 7-deep register
// ring; the vertical 7-tap consumes the ring. No LDS scratch for mu/mu2.
__global__ __launch_bounds__(256, 4) void piqe_main_kernel(
    const float* __restrict__ x, const unsigned int* __restrict__ maxbits,
    float* __restrict__ contrib_sum, unsigned int* __restrict__ nhsa)
{
    __shared__ float s_img[SIW * SI];    // 70 rows x 71 stride; later holds n in-place
    __shared__ float s_c;
    __shared__ unsigned int s_a;

    const int tid = threadIdx.x;
    const int b = blockIdx.z;
    const int ox = blockIdx.x * TILE;
    const int oy = blockIdx.y * TILE;
    const float* img0 = x + (size_t)b * (size_t)(IH * IW);
    const float scale = 255.0f / __uint_as_float(maxbits[b]);

    if (tid == 0) { s_c = 0.0f; s_a = 0u; }

    // Phase A: load 70x70 halo tile, edge-clamped, img = round(255*x/max)
    for (int i = tid; i < SIW * SIW; i += 256) {
        int r = i / SIW, c = i - r * SIW;
        int gy = oy + r - HALO; gy = max(0, min(IH - 1, gy));
        int gx = ox + c - HALO; gx = max(0, min(IW - 1, gx));
        s_img[r * SI + c] = rintf(img0[(size_t)gy * IW + gx] * scale);
    }
    __syncthreads();

    const float gk[7] = {G0, G1, G2, G3, G2, G1, G0};

    // Phase B+C fused: stream 22 halo rows through a 7-deep ring of
    // horizontal-conv results (mu, mu2); emit vertical conv + MSCN per row.
    const int cc = tid & 63;          // output column 0..63
    const int gg = tid >> 6;          // row group 0..3
    const int r0 = gg * 16;           // first output row of this thread
    const float* bp = &s_img[r0 * SI + cc];

    float hm[7], h2[7], pv[4], nv[16];
#pragma unroll
    for (int j = 0; j < 22; ++j) {
        // horizontal 7-tap at halo row r0+j, centered on column cc
        float m = 0.0f, m2 = 0.0f, ctr = 0.0f;
#pragma unroll
        for (int k = 0; k < 7; ++k) {
            float v = bp[j * SI + k];
            if (k == 3) ctr = v;               // center pixel of this row
            m = fmaf(gk[k], v, m);
            m2 = fmaf(gk[k] * v, v, m2);
        }
        hm[j % 7] = m;
        h2[j % 7] = m2;
        if (j >= 3 && j <= 18) pv[(j - 3) & 3] = ctr;   // pixel for output row j-3
        if (j >= 6) {
            const int r = j - 6;               // output row ready
            float vm = 0.0f, vm2 = 0.0f;
#pragma unroll
            for (int k = 0; k < 7; ++k) {
                vm = fmaf(gk[k], hm[(r + k) % 7], vm);
                vm2 = fmaf(gk[k], h2[(r + k) % 7], vm2);
            }
            float sd = fsqrt_f(fabsf(vm2 - vm * vm));
            nv[r] = (pv[r & 3] - vm) * frcp_f(sd + 1.0f);
        }
    }
    __syncthreads();     // all raw-img reads done -> safe to overwrite in place

    {
        float* wp = &s_img[(r0 + HALO) * SI + (cc + HALO)];
#pragma unroll
        for (int r = 0; r < 16; ++r) wp[r * SI] = nv[r];
    }
    __syncthreads();

    // Phase D: per-16x16-block stats. Wave w handles blocks w*4..w*4+3;
    // 16 lanes per block, lane L = row L of the block.
    const int lane = tid & 63;
    const int wv = tid >> 6;
    const int blk = wv * 4 + (lane >> 4);
    const int L = lane & 15;
    const int bi = blk >> 2, bj = blk & 3;
    const float* np0 = &s_img[(HALO + bi * 16) * SI + (HALO + bj * 16)];

    float rv[16];
    float s1 = 0.0f, s2 = 0.0f;
#pragma unroll
    for (int k = 0; k < 16; ++k) {
        float v = np0[L * SI + k];
        rv[k] = v;
        s1 += v;
        s2 += v * v;
    }
    float c1 = rv[7] + rv[8];
    float c2 = rv[7] * rv[7] + rv[8] * rv[8];
    float u1 = s1 - rv[7] - rv[9];                       // sur: 14 cols (keep 8, drop 7,9)
    float u2 = s2 - rv[7] * rv[7] - rv[9] * rv[9];

    // Edge 11-window seg-std minima: lanes 0..3 of each block group
    float minstd = __builtin_inff();
    if (L < 4) {
        int offs, stp;
        if (L == 0)      { offs = 0;       stp = 1; }    // top row
        else if (L == 1) { offs = 15 * SI; stp = 1; }    // bottom row
        else if (L == 2) { offs = 0;       stp = SI; }   // left col
        else             { offs = 15;      stp = SI; }   // right col
        float e[16];
#pragma unroll
        for (int k = 0; k < 16; ++k) e[k] = np0[offs + k * stp];
        float w1 = 0.0f, w2 = 0.0f;
#pragma unroll
        for (int k = 0; k < 6; ++k) { w1 += e[k]; w2 += e[k] * e[k]; }
#pragma unroll
        for (int i = 0; i < 11; ++i) {
            float var = (w2 - w1 * w1 * (1.0f / 6.0f)) * (1.0f / 5.0f);
            minstd = fminf(minstd, fsqrt_f(fmaxf(var, 0.0f)));
            if (i < 10) {
                w1 += e[i + 6] - e[i];
                w2 += e[i + 6] * e[i + 6] - e[i] * e[i];
            }
        }
    }

    // Butterfly reductions within each 16-lane group
#pragma unroll
    for (int m = 1; m < 16; m <<= 1) {
        s1 += __shfl_xor(s1, m);
        s2 += __shfl_xor(s2, m);
        c1 += __shfl_xor(c1, m);
        c2 += __shfl_xor(c2, m);
        u1 += __shfl_xor(u1, m);
        u2 += __shfl_xor(u2, m);
        minstd = fminf(minstd, __shfl_xor(minstd, m));
    }

    if (L == 0) {
        float bv = fmaxf((s2 - s1 * s1 * (1.0f / 256.0f)) * (1.0f / 255.0f), 0.0f);
        bool active = bv > ACT_TH;
        float cstd = fsqrt_f(fmaxf((c2 - c1 * c1 * (1.0f / 32.0f)) * (1.0f / 31.0f), 0.0f));
        float sstd = fsqrt_f(fmaxf((u2 - u1 * u1 * (1.0f / 224.0f)) * (1.0f / 223.0f), 0.0f));
        float csd = cstd * frcp_f(sstd);         // 0*rcp(0)=0*inf -> NaN (matches ref 0/0)
        if (csd != csd) csd = 0.0f;              // jnp.where(isnan(csd), 0, csd)
        float sigma = fsqrt_f(bv);
        float beta = fabsf(sigma - csd) * frcp_f(fmaxf(sigma, csd));
        bool wnc = sigma > 2.0f * beta;          // NaN beta -> false (matches)
        bool impaired = minstd < IMP_TH;
        if (active) {
            float contrib = (impaired ? (1.0f - bv) : 0.0f) + (wnc ? bv : 0.0f);
            atomicAdd(&s_c, contrib);
            atomicAdd(&s_a, 1u);
        }
    }
    __syncthreads();
    if (tid == 0) {
        atomicAdd(&contrib_sum[b], s_c);
        atomicAdd(&nhsa[b], s_a);
    }
}

// ---------------- Kernel 3: final score ----------------------------------
__global__ void piqe_finish_kernel(const float* __restrict__ contrib_sum,
                                   const unsigned int* __restrict__ nhsa,
                                   float* __restrict__ out)
{
    int b = threadIdx.x;
    if (b < NBATCH)
        out[b] = (contrib_sum[b] + 1.0f) / (1.0f + (float)nhsa[b]) * 100.0f;
}

extern "C" void kernel_launch(void* const* d_in, const int* in_sizes, int n_in,
                              void* d_out, int out_size, void* d_ws, size_t ws_size,
                              hipStream_t stream)
{
    const float* x = (const float*)d_in[0];
    float* out = (float*)d_out;

    unsigned int* maxbits = (unsigned int*)d_ws;                    // 8 u32
    float* contrib = (float*)((char*)d_ws + 32);                    // 8 f32
    unsigned int* nhsa = (unsigned int*)((char*)d_ws + 64);         // 8 u32

    hipMemsetAsync(d_ws, 0, 96, stream);
    batch_max_kernel<<<dim3(128, NBATCH), 256, 0, stream>>>(x, maxbits);
    piqe_main_kernel<<<dim3(IW / TILE, IH / TILE, NBATCH), 256, 0, stream>>>(
        x, maxbits, contrib, nhsa);
    piqe_finish_kernel<<<1, 64, 0, stream>>>(contrib, nhsa, out);
}